// Round 1
// baseline (1692.961 us; speedup 1.0000x reference)
//
#include <hip/hip_runtime.h>
#include <hip/hip_bf16.h>
#include <cstdint>

// Problem constants (fixed by the reference)
#define NB 4
#define NH 128
#define NW 128
#define NC 256
#define NFF 1024
#define NE 4
#define NPATCH 4096   // B * 32 * 32
#define PPB 4         // patches per ffn block
#define BM 64         // token rows per ffn block (PPB*16)
#define FFC 128       // FF chunk streamed through LDS

typedef __attribute__((ext_vector_type(8))) short short8;
typedef __attribute__((ext_vector_type(4))) float f32x4;

__device__ __forceinline__ unsigned short f2b(float f) {
  union { float f; uint32_t u; } v; v.f = f;
  uint32_t u = v.u + 0x7FFFu + ((v.u >> 16) & 1u);   // RNE
  return (unsigned short)(u >> 16);
}

// ---------------- weight fp32 -> bf16 ----------------
__global__ __launch_bounds__(256) void convert_kernel(
    const float* __restrict__ W1, const float* __restrict__ W2,
    unsigned short* __restrict__ W1b, unsigned short* __restrict__ W2b, int n) {
  int i = blockIdx.x * blockDim.x + threadIdx.x;
  if (i < n) {
    W1b[i] = f2b(W1[i]);
    W2b[i] = f2b(W2[i]);
  }
}

// ---------------- router: means -> logits -> softmax -> top2 -> lists ----------------
__global__ __launch_bounds__(256) void router_kernel(
    const float* __restrict__ x, const float* __restrict__ Wg,
    int* __restrict__ cnt, int* __restrict__ plist, float* __restrict__ wlist) {
  int p = blockIdx.x;                 // 0..4095
  int b = p >> 10, pi = p & 1023;
  int phi = pi >> 5, pwi = pi & 31;
  int c = threadIdx.x;                // 0..255 = channel

  const float* base = x + (((size_t)(b * NH + phi * 4) * NW) + pwi * 4) * NC + c;
  float s = 0.f;
#pragma unroll
  for (int i = 0; i < 4; i++)
#pragma unroll
    for (int j = 0; j < 4; j++)
      s += base[(i * NW + j) * NC];
  float mean = s * (1.f / 16.f);

  __shared__ float m_lds[NC];
  __shared__ double logit_lds[NE];
  m_lds[c] = mean;
  __syncthreads();

  int wid = c >> 6, lane = c & 63;    // wave w computes logit for expert w
  {
    const float* wg = Wg + wid * NC;
    double acc = 0.0;
#pragma unroll
    for (int q = 0; q < 4; q++)
      acc += (double)m_lds[lane + q * 64] * (double)wg[lane + q * 64];
    for (int off = 32; off; off >>= 1) acc += __shfl_down(acc, off);
    if (lane == 0) logit_lds[wid] = acc;
  }
  __syncthreads();

  if (c == 0) {
    double l[NE], pp[NE];
    double mx = -1e300;
#pragma unroll
    for (int i = 0; i < NE; i++) { l[i] = logit_lds[i]; mx = fmax(mx, l[i]); }
    double sum = 0.0;
#pragma unroll
    for (int i = 0; i < NE; i++) { pp[i] = exp(l[i] - mx); sum += pp[i]; }
#pragma unroll
    for (int i = 0; i < NE; i++) pp[i] /= sum;
    // top-2, ties -> lower index (lax.top_k semantics)
    int i1 = 0; double p1 = pp[0];
    for (int i = 1; i < NE; i++) if (pp[i] > p1) { p1 = pp[i]; i1 = i; }
    int i2 = -1; double p2 = -1.0;
    for (int i = 0; i < NE; i++) {
      if (i == i1) continue;
      if (pp[i] > p2) { p2 = pp[i]; i2 = i; }
    }
    double den = p1 + p2 + 1e-9;
    float w1 = (float)(p1 / den), w2 = (float)(p2 / den);
    int pos0 = atomicAdd(&cnt[0 * NE + i1], 1);
    plist[(0 * NE + i1) * NPATCH + pos0] = p;
    wlist[(0 * NE + i1) * NPATCH + pos0] = w1;
    int pos1 = atomicAdd(&cnt[1 * NE + i2], 1);
    plist[(1 * NE + i2) * NPATCH + pos1] = p;
    wlist[(1 * NE + i2) * NPATCH + pos1] = w2;
  }
}

// ---------------- expert FFN (fused GEMM1 -> gelu -> GEMM2) ----------------
__global__ __launch_bounds__(256) void ffn_kernel(
    const float* __restrict__ x, const float* __restrict__ b1,
    const float* __restrict__ b2, const unsigned short* __restrict__ W1b,
    const unsigned short* __restrict__ W2b, const int* __restrict__ cnt,
    const int* __restrict__ plist, const float* __restrict__ wlist,
    float* __restrict__ out, int slot) {
  __shared__ unsigned short Xl[BM * NC];    // 32 KiB, XOR-swizzled, row stride 512B
  __shared__ unsigned short Hl[BM * FFC];   // 16 KiB, XOR-swizzled, row stride 256B
  __shared__ int s_pid[PPB];
  __shared__ float s_w[PPB];

  int e = blockIdx.y;
  int le = slot * NE + e;
  int n = cnt[le];
  int tile = blockIdx.x;
  if (tile * PPB >= n) return;

  int tid = threadIdx.x, lane = tid & 63, wid = tid >> 6;

  if (tid < PPB) {
    int k = tile * PPB + tid;
    s_pid[tid] = (k < n) ? plist[le * NPATCH + k] : -1;
    s_w[tid]   = (k < n) ? wlist[le * NPATCH + k] : 0.f;
  }
  __syncthreads();

  // ---- gather tokens -> bf16 LDS (swizzled) ----
  {
    int r  = tid >> 2;            // 0..63 token row
    int c0 = (tid & 3) * 64;      // 64 channels per thread
    int pid = s_pid[r >> 4];
    int t = r & 15;
    if (pid >= 0) {
      int b = pid >> 10, pi = pid & 1023;
      int phi = pi >> 5, pwi = pi & 31;
      const float* src =
          x + (((size_t)(b * NH + phi * 4 + (t >> 2)) * NW) + pwi * 4 + (t & 3)) * NC + c0;
#pragma unroll
      for (int q = 0; q < 16; q++) {
        float4 v = *reinterpret_cast<const float4*>(src + q * 4);
        ushort4 h;
        h.x = f2b(v.x); h.y = f2b(v.y); h.z = f2b(v.z); h.w = f2b(v.w);
        int boff = (r * 512 + (c0 + q * 4) * 2) ^ ((r & 7) << 4);
        *reinterpret_cast<ushort4*>((char*)Xl + boff) = h;
      }
    } else {
      ushort4 h; h.x = h.y = h.z = h.w = 0;
#pragma unroll
      for (int q = 0; q < 16; q++) {
        int boff = (r * 512 + (c0 + q * 4) * 2) ^ ((r & 7) << 4);
        *reinterpret_cast<ushort4*>((char*)Xl + boff) = h;
      }
    }
  }
  __syncthreads();

  f32x4 acc2[16];
#pragma unroll
  for (int i = 0; i < 16; i++)
#pragma unroll
    for (int j = 0; j < 4; j++) acc2[i][j] = 0.f;

  int row0 = wid * 16;                 // wave -> one patch (16 rows)
  int arow = row0 + (lane & 15);
  int kgrp = (lane >> 4) * 8;

  const unsigned short* W1e = W1b + (size_t)e * NFF * NC;
  const unsigned short* W2e = W2b + (size_t)e * NC * NFF;
  const float* b1e = b1 + e * NFF;
  const float* b2e = b2 + e * NC;

  for (int fc = 0; fc < NFF / FFC; fc++) {
    // ---- GEMM1: H[16, FFC] = X[16,256] @ W1_chunk^T ----
    f32x4 acc1[8];
#pragma unroll
    for (int i = 0; i < 8; i++)
#pragma unroll
      for (int j = 0; j < 4; j++) acc1[i][j] = 0.f;

#pragma unroll
    for (int ks = 0; ks < 8; ks++) {           // K = 256
      int k = ks * 32 + kgrp;
      int boff = (arow * 512 + k * 2) ^ ((arow & 7) << 4);
      short8 a = *reinterpret_cast<const short8*>((const char*)Xl + boff);
#pragma unroll
      for (int ft = 0; ft < 8; ft++) {
        int f = fc * FFC + ft * 16 + (lane & 15);
        short8 bw = *reinterpret_cast<const short8*>(W1e + (size_t)f * NC + k);
        acc1[ft] = __builtin_amdgcn_mfma_f32_16x16x32_bf16(a, bw, acc1[ft], 0, 0, 0);
      }
    }

    __syncthreads();   // previous GEMM2 finished reading Hl

    // ---- bias + exact gelu -> bf16 H in LDS ----
#pragma unroll
    for (int ft = 0; ft < 8; ft++) {
      int col = ft * 16 + (lane & 15);
      float bias = b1e[fc * FFC + col];
#pragma unroll
      for (int i = 0; i < 4; i++) {
        int rr = row0 + (lane >> 4) * 4 + i;
        float vv = acc1[ft][i] + bias;
        float g = 0.5f * vv * (1.f + erff(vv * 0.70710678118654752f));
        int boff = (rr * 256 + col * 2) ^ ((rr & 7) << 4);
        *reinterpret_cast<unsigned short*>((char*)Hl + boff) = f2b(g);
      }
    }
    __syncthreads();

    // ---- GEMM2: Y[16,256] += H[16,FFC] @ W2_chunk^T ----
    short8 a2[4];
#pragma unroll
    for (int ks = 0; ks < 4; ks++) {
      int f = ks * 32 + kgrp;
      int boff = (arow * 256 + f * 2) ^ ((arow & 7) << 4);
      a2[ks] = *reinterpret_cast<const short8*>((const char*)Hl + boff);
    }
#pragma unroll
    for (int ct = 0; ct < 16; ct++) {
      int c = ct * 16 + (lane & 15);
#pragma unroll
      for (int ks = 0; ks < 4; ks++) {
        int f = fc * FFC + ks * 32 + kgrp;
        short8 bw = *reinterpret_cast<const short8*>(W2e + (size_t)c * NFF + f);
        acc2[ct] = __builtin_amdgcn_mfma_f32_16x16x32_bf16(a2[ks], bw, acc2[ct], 0, 0, 0);
      }
    }
  }

  // ---- epilogue: out = / += w * (Y + b2) ----
  int pid = s_pid[wid];
  if (pid < 0) return;
  float wgt = s_w[wid];
  int b = pid >> 10, pi = pid & 1023;
  int phi = pi >> 5, pwi = pi & 31;
#pragma unroll
  for (int i = 0; i < 4; i++) {
    int t = (lane >> 4) * 4 + i;   // token within patch
    float* dst =
        out + (((size_t)(b * NH + phi * 4 + (t >> 2)) * NW) + pwi * 4 + (t & 3)) * NC;
#pragma unroll
    for (int ct = 0; ct < 16; ct++) {
      int c = ct * 16 + (lane & 15);
      float val = wgt * (acc2[ct][i] + b2e[c]);
      if (slot == 0) dst[c] = val;
      else dst[c] += val;
    }
  }
}

extern "C" void kernel_launch(void* const* d_in, const int* in_sizes, int n_in,
                              void* d_out, int out_size, void* d_ws, size_t ws_size,
                              hipStream_t stream) {
  const float* x  = (const float*)d_in[0];
  const float* Wg = (const float*)d_in[1];
  const float* W1 = (const float*)d_in[2];
  const float* b1 = (const float*)d_in[3];
  const float* W2 = (const float*)d_in[4];
  const float* b2 = (const float*)d_in[5];
  float* out = (float*)d_out;

  char* ws = (char*)d_ws;
  unsigned short* W1b = (unsigned short*)ws;                                  // 2 MiB
  unsigned short* W2b = (unsigned short*)(ws + (size_t)2 * 1024 * 1024);      // 2 MiB
  int*   cnt   = (int*)(ws + (size_t)4 * 1024 * 1024);                        // 8 ints
  int*   plist = (int*)(ws + (size_t)4 * 1024 * 1024 + 256);                  // 128 KiB
  float* wlist = (float*)(ws + (size_t)4 * 1024 * 1024 + 256 +
                          (size_t)2 * NE * NPATCH * sizeof(int));             // 128 KiB

  hipMemsetAsync(cnt, 0, 2 * NE * sizeof(int), stream);
  convert_kernel<<<dim3(4096), dim3(256), 0, stream>>>(W1, W2, W1b, W2b, NE * NFF * NC);
  router_kernel<<<dim3(NPATCH), dim3(256), 0, stream>>>(x, Wg, cnt, plist, wlist);

  dim3 g(NPATCH / PPB, NE, 1);
  ffn_kernel<<<g, dim3(256), 0, stream>>>(x, b1, b2, W1b, W2b, cnt, plist, wlist, out, 0);
  ffn_kernel<<<g, dim3(256), 0, stream>>>(x, b1, b2, W1b, W2b, cnt, plist, wlist, out, 1);
}

// Round 2
// 558.167 us; speedup vs baseline: 3.0331x; 3.0331x over previous
//
#include <hip/hip_runtime.h>
#include <hip/hip_bf16.h>
#include <cstdint>

// Problem constants (fixed by the reference)
#define NB 4
#define NH 128
#define NW 128
#define NC 256
#define NFF 1024
#define NE 4
#define NPATCH 4096   // B * 32 * 32
#define PPB 4         // patches per ffn block
#define BM 64         // token rows per ffn block (PPB*16)
#define FFC 256       // FF chunk streamed through LDS
#define NCHUNK (NFF / FFC)

typedef __attribute__((ext_vector_type(8))) short short8;
typedef __attribute__((ext_vector_type(4))) float f32x4;

__device__ __forceinline__ unsigned short f2b(float f) {
  union { float f; uint32_t u; } v; v.f = f;
  uint32_t u = v.u + 0x7FFFu + ((v.u >> 16) & 1u);   // RNE
  return (unsigned short)(u >> 16);
}

// ---------------- weight fp32 -> bf16 ----------------
__global__ __launch_bounds__(256) void convert_kernel(
    const float* __restrict__ W1, const float* __restrict__ W2,
    unsigned short* __restrict__ W1b, unsigned short* __restrict__ W2b, int n) {
  int i = blockIdx.x * blockDim.x + threadIdx.x;
  if (i < n) {
    W1b[i] = f2b(W1[i]);
    W2b[i] = f2b(W2[i]);
  }
}

// ---------------- router: means -> logits -> softmax -> top2 -> lists ----------------
__global__ __launch_bounds__(256) void router_kernel(
    const float* __restrict__ x, const float* __restrict__ Wg,
    int* __restrict__ cnt, int* __restrict__ plist, float* __restrict__ wlist) {
  int p = blockIdx.x;                 // 0..4095
  int b = p >> 10, pi = p & 1023;
  int phi = pi >> 5, pwi = pi & 31;
  int c = threadIdx.x;                // 0..255 = channel

  const float* base = x + (((size_t)(b * NH + phi * 4) * NW) + pwi * 4) * NC + c;
  float s = 0.f;
#pragma unroll
  for (int i = 0; i < 4; i++)
#pragma unroll
    for (int j = 0; j < 4; j++)
      s += base[(i * NW + j) * NC];
  float mean = s * (1.f / 16.f);

  __shared__ float m_lds[NC];
  __shared__ double logit_lds[NE];
  m_lds[c] = mean;
  __syncthreads();

  int wid = c >> 6, lane = c & 63;    // wave w computes logit for expert w
  {
    const float* wg = Wg + wid * NC;
    double acc = 0.0;
#pragma unroll
    for (int q = 0; q < 4; q++)
      acc += (double)m_lds[lane + q * 64] * (double)wg[lane + q * 64];
    for (int off = 32; off; off >>= 1) acc += __shfl_down(acc, off);
    if (lane == 0) logit_lds[wid] = acc;
  }
  __syncthreads();

  if (c == 0) {
    double l[NE], pp[NE];
    double mx = -1e300;
#pragma unroll
    for (int i = 0; i < NE; i++) { l[i] = logit_lds[i]; mx = fmax(mx, l[i]); }
    double sum = 0.0;
#pragma unroll
    for (int i = 0; i < NE; i++) { pp[i] = exp(l[i] - mx); sum += pp[i]; }
#pragma unroll
    for (int i = 0; i < NE; i++) pp[i] /= sum;
    // top-2, ties -> lower index (lax.top_k semantics)
    int i1 = 0; double p1 = pp[0];
    for (int i = 1; i < NE; i++) if (pp[i] > p1) { p1 = pp[i]; i1 = i; }
    int i2 = -1; double p2 = -1.0;
    for (int i = 0; i < NE; i++) {
      if (i == i1) continue;
      if (pp[i] > p2) { p2 = pp[i]; i2 = i; }
    }
    double den = p1 + p2 + 1e-9;
    float w1 = (float)(p1 / den), w2 = (float)(p2 / den);
    int pos0 = atomicAdd(&cnt[0 * NE + i1], 1);
    plist[(0 * NE + i1) * NPATCH + pos0] = p;
    wlist[(0 * NE + i1) * NPATCH + pos0] = w1;
    int pos1 = atomicAdd(&cnt[1 * NE + i2], 1);
    plist[(1 * NE + i2) * NPATCH + pos1] = p;
    wlist[(1 * NE + i2) * NPATCH + pos1] = w2;
  }
}

// ---------------- expert FFN (fused GEMM1 -> gelu -> GEMM2) ----------------
// Each block: 4 patches (64 token rows) of one (slot, expert) assignment list.
// Wave w owns f-strip [w*64, w*64+64) of each FF chunk (GEMM1, swapped operands)
// and c-strip [w*64, w*64+64) of the output (GEMM2). Every weight fragment
// feeds 4 MFMAs (4 row tiles); W1+W2 read exactly once per block.
// bid&7 = e*2+slot -> XCD affinity: 1MB weight set per XCD L2.
__global__ __launch_bounds__(256, 2) void ffn_kernel(
    const float* __restrict__ x, const float* __restrict__ b1,
    const float* __restrict__ b2, const unsigned short* __restrict__ W1b,
    const unsigned short* __restrict__ W2b, const int* __restrict__ cnt,
    const int* __restrict__ plist, const float* __restrict__ wlist,
    float* __restrict__ out0, float* __restrict__ out1, int mode) {
  __shared__ unsigned short Xl[BM * NC];    // 32 KiB, swizzled, row stride 512B
  __shared__ unsigned short Hl[BM * FFC];   // 32 KiB, swizzled, row stride 512B
  __shared__ int s_pid[PPB];
  __shared__ float s_w[PPB];

  int bid = blockIdx.x;
  int grp = bid & 7;                // -> XCD
  int e = grp >> 1, slot = grp & 1;
  int tile = bid >> 3;
  int le = slot * NE + e;
  int n = cnt[le];
  if (tile * PPB >= n) return;

  int tid = threadIdx.x, lane = tid & 63, wid = tid >> 6;
  int l15 = lane & 15;
  int kgrp = (lane >> 4) * 8;

  if (tid < PPB) {
    int k = tile * PPB + tid;
    s_pid[tid] = (k < n) ? plist[le * NPATCH + k] : -1;
    s_w[tid]   = (k < n) ? wlist[le * NPATCH + k] : 0.f;
  }
  __syncthreads();

  // ---- gather tokens -> bf16 LDS (swizzled) ----
  {
    int r  = tid >> 2;            // 0..63 token row
    int c0 = (tid & 3) * 64;      // 64 channels per thread
    int pid = s_pid[r >> 4];
    int t = r & 15;
    if (pid >= 0) {
      int b = pid >> 10, pi = pid & 1023;
      int phi = pi >> 5, pwi = pi & 31;
      const float* src =
          x + (((size_t)(b * NH + phi * 4 + (t >> 2)) * NW) + pwi * 4 + (t & 3)) * NC + c0;
#pragma unroll
      for (int q = 0; q < 16; q++) {
        float4 v = *reinterpret_cast<const float4*>(src + q * 4);
        ushort4 h;
        h.x = f2b(v.x); h.y = f2b(v.y); h.z = f2b(v.z); h.w = f2b(v.w);
        int boff = (r * 512 + (c0 + q * 4) * 2) ^ ((r & 7) << 4);
        *reinterpret_cast<ushort4*>((char*)Xl + boff) = h;
      }
    } else {
      ushort4 h; h.x = h.y = h.z = h.w = 0;
#pragma unroll
      for (int q = 0; q < 16; q++) {
        int boff = (r * 512 + (c0 + q * 4) * 2) ^ ((r & 7) << 4);
        *reinterpret_cast<ushort4*>((char*)Xl + boff) = h;
      }
    }
  }
  __syncthreads();

  f32x4 acc2[4][4];   // [ct][rt] : Y[rt*16.., wid*64 + ct*16..]
#pragma unroll
  for (int a = 0; a < 4; a++)
#pragma unroll
    for (int b = 0; b < 4; b++)
#pragma unroll
      for (int j = 0; j < 4; j++) acc2[a][b][j] = 0.f;

  const unsigned short* W1e = W1b + (size_t)e * NFF * NC;
  const unsigned short* W2e = W2b + (size_t)e * NC * NFF;
  const float* b1e = b1 + e * NFF;
  const float* b2e = b2 + e * NC;

  for (int fc = 0; fc < NCHUNK; fc++) {
    // ---- GEMM1 (swapped): H^T[f, token] += W1[f,k] * X[token,k] ----
    f32x4 acc1[4][4];   // [ftl][nt]
#pragma unroll
    for (int a = 0; a < 4; a++)
#pragma unroll
      for (int b = 0; b < 4; b++)
#pragma unroll
        for (int j = 0; j < 4; j++) acc1[a][b][j] = 0.f;

#pragma unroll
    for (int ks = 0; ks < 8; ks++) {        // K = NC = 256
      int k = ks * 32 + kgrp;
      short8 bX[4];
#pragma unroll
      for (int nt = 0; nt < 4; nt++) {
        int row = nt * 16 + l15;
        int boff = (row * 512 + k * 2) ^ ((row & 7) << 4);
        bX[nt] = *reinterpret_cast<const short8*>((const char*)Xl + boff);
      }
#pragma unroll
      for (int ftl = 0; ftl < 4; ftl++) {
        int f = fc * FFC + wid * 64 + ftl * 16 + l15;
        short8 aW = *reinterpret_cast<const short8*>(W1e + (size_t)f * NC + k);
#pragma unroll
        for (int nt = 0; nt < 4; nt++)
          acc1[ftl][nt] = __builtin_amdgcn_mfma_f32_16x16x32_bf16(aW, bX[nt], acc1[ftl][nt], 0, 0, 0);
      }
    }

    __syncthreads();   // previous GEMM2 finished reading Hl

    // ---- bias + exact gelu -> bf16 Hl[token][f] (packed b64 writes) ----
#pragma unroll
    for (int ftl = 0; ftl < 4; ftl++) {
#pragma unroll
      for (int nt = 0; nt < 4; nt++) {
        int token = nt * 16 + l15;
        int f0 = wid * 64 + ftl * 16 + (lane >> 4) * 4;   // f within chunk
        ushort4 hp;
        float vv, g;
        vv = acc1[ftl][nt][0] + b1e[fc * FFC + f0 + 0];
        g = 0.5f * vv * (1.f + erff(vv * 0.70710678118654752f)); hp.x = f2b(g);
        vv = acc1[ftl][nt][1] + b1e[fc * FFC + f0 + 1];
        g = 0.5f * vv * (1.f + erff(vv * 0.70710678118654752f)); hp.y = f2b(g);
        vv = acc1[ftl][nt][2] + b1e[fc * FFC + f0 + 2];
        g = 0.5f * vv * (1.f + erff(vv * 0.70710678118654752f)); hp.z = f2b(g);
        vv = acc1[ftl][nt][3] + b1e[fc * FFC + f0 + 3];
        g = 0.5f * vv * (1.f + erff(vv * 0.70710678118654752f)); hp.w = f2b(g);
        int boff = (token * 512 + f0 * 2) ^ ((token & 7) << 4);
        *reinterpret_cast<ushort4*>((char*)Hl + boff) = hp;
      }
    }
    __syncthreads();   // Hl chunk ready

    // ---- GEMM2: Y[token, c] += H[token, f] * W2[c, f] ----
#pragma unroll
    for (int ks = 0; ks < 8; ks++) {        // K = FFC = 256
      int kf = ks * 32 + kgrp;
      short8 aH[4];
#pragma unroll
      for (int rt = 0; rt < 4; rt++) {
        int row = rt * 16 + l15;
        int boff = (row * 512 + kf * 2) ^ ((row & 7) << 4);
        aH[rt] = *reinterpret_cast<const short8*>((const char*)Hl + boff);
      }
#pragma unroll
      for (int ct = 0; ct < 4; ct++) {
        int c = wid * 64 + ct * 16 + l15;
        short8 bW = *reinterpret_cast<const short8*>(W2e + (size_t)c * NFF + fc * FFC + kf);
#pragma unroll
        for (int rt = 0; rt < 4; rt++)
          acc2[ct][rt] = __builtin_amdgcn_mfma_f32_16x16x32_bf16(aH[rt], bW, acc2[ct][rt], 0, 0, 0);
      }
    }
  }

  // ---- epilogue: out_slot = w * (Y + b2) ----
  float* obase = (slot == 0) ? out0 : out1;
#pragma unroll
  for (int rt = 0; rt < 4; rt++) {
    int pid = s_pid[rt];
    if (pid < 0) continue;
    float wgt = s_w[rt];
    int b = pid >> 10, pi = pid & 1023;
    int phi = pi >> 5, pwi = pi & 31;
#pragma unroll
    for (int i = 0; i < 4; i++) {
      int t = (lane >> 4) * 4 + i;   // token within patch
      float* dst =
          obase + (((size_t)(b * NH + phi * 4 + (t >> 2)) * NW) + pwi * 4 + (t & 3)) * NC;
#pragma unroll
      for (int ct = 0; ct < 4; ct++) {
        int c = wid * 64 + ct * 16 + l15;
        float val = wgt * (acc2[ct][rt][i] + b2e[c]);
        if (mode == 0) dst[c] = val;
        else atomicAdd(&dst[c], val);
      }
    }
  }
}

// ---------------- combine: out += y1 ----------------
__global__ __launch_bounds__(256) void combine_kernel(
    float* __restrict__ out, const float* __restrict__ y1, int n4) {
  int i = blockIdx.x * blockDim.x + threadIdx.x;
  int stride = gridDim.x * blockDim.x;
  for (; i < n4; i += stride) {
    float4 a = reinterpret_cast<float4*>(out)[i];
    float4 b = reinterpret_cast<const float4*>(y1)[i];
    a.x += b.x; a.y += b.y; a.z += b.z; a.w += b.w;
    reinterpret_cast<float4*>(out)[i] = a;
  }
}

extern "C" void kernel_launch(void* const* d_in, const int* in_sizes, int n_in,
                              void* d_out, int out_size, void* d_ws, size_t ws_size,
                              hipStream_t stream) {
  const float* x  = (const float*)d_in[0];
  const float* Wg = (const float*)d_in[1];
  const float* W1 = (const float*)d_in[2];
  const float* b1 = (const float*)d_in[3];
  const float* W2 = (const float*)d_in[4];
  const float* b2 = (const float*)d_in[5];
  float* out = (float*)d_out;

  char* ws = (char*)d_ws;
  unsigned short* W1b = (unsigned short*)ws;                                  // 2 MiB
  unsigned short* W2b = (unsigned short*)(ws + (size_t)2 * 1024 * 1024);      // 2 MiB
  int*   cnt   = (int*)(ws + (size_t)4 * 1024 * 1024);                        // 8 ints
  int*   plist = (int*)(ws + (size_t)4 * 1024 * 1024 + 256);                  // 128 KiB
  float* wlist = (float*)(ws + (size_t)4 * 1024 * 1024 + 256 +
                          (size_t)2 * NE * NPATCH * sizeof(int));             // 128 KiB
  float* y1buf = (float*)(ws + (size_t)8 * 1024 * 1024);                      // 64 MiB

  size_t need = (size_t)8 * 1024 * 1024 + (size_t)NB * NH * NW * NC * sizeof(float);
  int mode = (ws_size >= need) ? 0 : 1;   // 0: slot buffers + combine, 1: atomic

  hipMemsetAsync(cnt, 0, 2 * NE * sizeof(int), stream);
  if (mode == 1)
    hipMemsetAsync(out, 0, (size_t)out_size * sizeof(float), stream);

  convert_kernel<<<dim3(4096), dim3(256), 0, stream>>>(W1, W2, W1b, W2b, NE * NFF * NC);
  router_kernel<<<dim3(NPATCH), dim3(256), 0, stream>>>(x, Wg, cnt, plist, wlist);

  float* out1 = (mode == 0) ? y1buf : out;
  ffn_kernel<<<dim3(8192), dim3(256), 0, stream>>>(
      x, b1, b2, W1b, W2b, cnt, plist, wlist, out, out1, mode);

  if (mode == 0) {
    int n4 = NB * NH * NW * NC / 4;
    combine_kernel<<<dim3(2048), dim3(256), 0, stream>>>(out, y1buf, n4);
  }
}

// Round 3
// 466.049 us; speedup vs baseline: 3.6326x; 1.1977x over previous
//
#include <hip/hip_runtime.h>
#include <hip/hip_bf16.h>
#include <cstdint>

// Problem constants (fixed by the reference)
#define NB 4
#define NH 128
#define NW 128
#define NC 256
#define NFF 1024
#define NE 4
#define NPATCH 4096   // B * 32 * 32
#define PPB 4         // patches per ffn block
#define BM 64         // token rows per ffn block (PPB*16)
#define FFC 128       // FF chunk streamed through LDS
#define NCHUNK (NFF / FFC)   // 8

typedef __attribute__((ext_vector_type(8))) short short8;
typedef __attribute__((ext_vector_type(8))) unsigned short ushort8;
typedef __attribute__((ext_vector_type(4))) float f32x4;

__device__ __forceinline__ unsigned short f2b(float f) {
  union { float f; uint32_t u; } v; v.f = f;
  uint32_t u = v.u + 0x7FFFu + ((v.u >> 16) & 1u);   // RNE
  return (unsigned short)(u >> 16);
}

// tanh-form GELU via sigmoid: x * sigmoid(1.5957691(x + 0.044715 x^3))
// max |diff| vs exact erf-gelu ~1e-3 (safe: bf16 h rounding is already ~4e-3)
__device__ __forceinline__ float gelu_f(float v) {
  float u = v * v;
  float t = __builtin_fmaf(u, 0.044715f, 1.0f) * v;
  float e = __builtin_amdgcn_exp2f(t * -2.3022083f);   // exp(-1.59577*t)
  return v * __builtin_amdgcn_rcpf(1.0f + e);
}

// barrier that drains LDS ops only (no vmcnt drain -> global loads stay in flight)
__device__ __forceinline__ void bar_lgkm() {
  asm volatile("s_waitcnt lgkmcnt(0)" ::: "memory");
  __builtin_amdgcn_s_barrier();
}

// ---------------- weight fp32 -> bf16 ----------------
__global__ __launch_bounds__(256) void convert_kernel(
    const float* __restrict__ W1, const float* __restrict__ W2,
    unsigned short* __restrict__ W1b, unsigned short* __restrict__ W2b, int n) {
  int i = blockIdx.x * blockDim.x + threadIdx.x;
  if (i < n) {
    W1b[i] = f2b(W1[i]);
    W2b[i] = f2b(W2[i]);
  }
}

// ---------------- router: means -> logits -> softmax -> top2 -> lists ----------------
__global__ __launch_bounds__(256) void router_kernel(
    const float* __restrict__ x, const float* __restrict__ Wg,
    int* __restrict__ cnt, int* __restrict__ plist, float* __restrict__ wlist) {
  int p = blockIdx.x;                 // 0..4095
  int b = p >> 10, pi = p & 1023;
  int phi = pi >> 5, pwi = pi & 31;
  int c = threadIdx.x;                // 0..255 = channel

  const float* base = x + (((size_t)(b * NH + phi * 4) * NW) + pwi * 4) * NC + c;
  float s = 0.f;
#pragma unroll
  for (int i = 0; i < 4; i++)
#pragma unroll
    for (int j = 0; j < 4; j++)
      s += base[(i * NW + j) * NC];
  float mean = s * (1.f / 16.f);

  __shared__ float m_lds[NC];
  __shared__ double logit_lds[NE];
  m_lds[c] = mean;
  __syncthreads();

  int wid = c >> 6, lane = c & 63;    // wave w computes logit for expert w
  {
    const float* wg = Wg + wid * NC;
    double acc = 0.0;
#pragma unroll
    for (int q = 0; q < 4; q++)
      acc += (double)m_lds[lane + q * 64] * (double)wg[lane + q * 64];
    for (int off = 32; off; off >>= 1) acc += __shfl_down(acc, off);
    if (lane == 0) logit_lds[wid] = acc;
  }
  __syncthreads();

  if (c == 0) {
    double l[NE], pp[NE];
    double mx = -1e300;
#pragma unroll
    for (int i = 0; i < NE; i++) { l[i] = logit_lds[i]; mx = fmax(mx, l[i]); }
    double sum = 0.0;
#pragma unroll
    for (int i = 0; i < NE; i++) { pp[i] = exp(l[i] - mx); sum += pp[i]; }
#pragma unroll
    for (int i = 0; i < NE; i++) pp[i] /= sum;
    // top-2, ties -> lower index (lax.top_k semantics)
    int i1 = 0; double p1 = pp[0];
    for (int i = 1; i < NE; i++) if (pp[i] > p1) { p1 = pp[i]; i1 = i; }
    int i2 = -1; double p2 = -1.0;
    for (int i = 0; i < NE; i++) {
      if (i == i1) continue;
      if (pp[i] > p2) { p2 = pp[i]; i2 = i; }
    }
    double den = p1 + p2 + 1e-9;
    float w1 = (float)(p1 / den), w2 = (float)(p2 / den);
    int pos0 = atomicAdd(&cnt[0 * NE + i1], 1);
    plist[(0 * NE + i1) * NPATCH + pos0] = p;
    wlist[(0 * NE + i1) * NPATCH + pos0] = w1;
    int pos1 = atomicAdd(&cnt[1 * NE + i2], 1);
    plist[(1 * NE + i2) * NPATCH + pos1] = p;
    wlist[(1 * NE + i2) * NPATCH + pos1] = w2;
  }
}

// ---------------- expert FFN (fused GEMM1 -> gelu -> GEMM2) ----------------
// Block: 4 patches (64 token rows) of one (slot, expert) list. Wave w owns
// f-strip [w*32, w*32+32) of each 128-wide FF chunk (GEMM1, swapped operands)
// and c-strip [w*64, w*64+64) of the output (GEMM2). Each weight fragment
// feeds 4 MFMAs; W1+W2 read once per block. bid&7 = e*2+slot -> XCD L2 affinity.
// Barriers are lgkm-only: weight loads stay in flight across phase boundaries.
__global__ __launch_bounds__(256, 3) void ffn_kernel(
    const float* __restrict__ x, const float* __restrict__ b1,
    const float* __restrict__ b2, const unsigned short* __restrict__ W1b,
    const unsigned short* __restrict__ W2b, const int* __restrict__ cnt,
    const int* __restrict__ plist, const float* __restrict__ wlist,
    float* __restrict__ out0, float* __restrict__ out1, int mode) {
  __shared__ unsigned short Xl[BM * NC];    // 32 KiB, swizzled, row stride 512B
  __shared__ unsigned short Hl[BM * FFC];   // 16 KiB, swizzled, row stride 256B

  int bid = blockIdx.x;
  int grp = bid & 7;                // -> XCD
  int e = grp >> 1, slot = grp & 1;
  int tile = bid >> 3;
  int le = slot * NE + e;
  int n = cnt[le];
  if (tile * PPB >= n) return;

  int tid = threadIdx.x, lane = tid & 63, wid = tid >> 6;
  int l15 = lane & 15;
  int kgrp = (lane >> 4) * 8;

  const int*   pl = plist + le * NPATCH + tile * PPB;
  const float* wl = wlist + le * NPATCH + tile * PPB;

  // ---- gather tokens -> bf16 LDS (swizzled, 16B writes) ----
  {
    int r  = tid >> 2;            // 0..63 token row; r>>4 == wid
    int c0 = (tid & 3) * 64;      // 64 channels per thread
    int pid = (tile * PPB + wid < n) ? pl[wid] : -1;
    int t = r & 15;
    if (pid >= 0) {
      int b = pid >> 10, pi = pid & 1023;
      int phi = pi >> 5, pwi = pi & 31;
      const float* src =
          x + (((size_t)(b * NH + phi * 4 + (t >> 2)) * NW) + pwi * 4 + (t & 3)) * NC + c0;
#pragma unroll
      for (int q = 0; q < 8; q++) {
        float4 v0 = *reinterpret_cast<const float4*>(src + q * 8);
        float4 v1 = *reinterpret_cast<const float4*>(src + q * 8 + 4);
        ushort8 h;
        h[0] = f2b(v0.x); h[1] = f2b(v0.y); h[2] = f2b(v0.z); h[3] = f2b(v0.w);
        h[4] = f2b(v1.x); h[5] = f2b(v1.y); h[6] = f2b(v1.z); h[7] = f2b(v1.w);
        int boff = (r * 512 + (c0 + q * 8) * 2) ^ ((r & 7) << 4);
        *reinterpret_cast<ushort8*>((char*)Xl + boff) = h;
      }
    } else {
      ushort8 h = (ushort8)0;
#pragma unroll
      for (int q = 0; q < 8; q++) {
        int boff = (r * 512 + (c0 + q * 8) * 2) ^ ((r & 7) << 4);
        *reinterpret_cast<ushort8*>((char*)Xl + boff) = h;
      }
    }
  }
  bar_lgkm();

  f32x4 acc2[4][4];   // [ct][rt] : Y[rt*16.., wid*64 + ct*16..]
#pragma unroll
  for (int a = 0; a < 4; a++)
#pragma unroll
    for (int b = 0; b < 4; b++)
#pragma unroll
      for (int j = 0; j < 4; j++) acc2[a][b][j] = 0.f;

  const unsigned short* W1e = W1b + (size_t)e * NFF * NC;
  const unsigned short* W2e = W2b + (size_t)e * NC * NFF;
  const float* b1e = b1 + e * NFF;
  const float* b2e = b2 + e * NC;

  for (int fc = 0; fc < NCHUNK; fc++) {
    // ---- GEMM1 (swapped): H^T[f, token] += W1[f,k] * X[token,k] ----
    f32x4 acc1[2][4];   // [ftl][nt]
#pragma unroll
    for (int a = 0; a < 2; a++)
#pragma unroll
      for (int b = 0; b < 4; b++)
#pragma unroll
        for (int j = 0; j < 4; j++) acc1[a][b][j] = 0.f;

#pragma unroll
    for (int ks = 0; ks < 8; ks++) {        // K = NC = 256
      int k = ks * 32 + kgrp;
      short8 bX[4];
#pragma unroll
      for (int nt = 0; nt < 4; nt++) {
        int row = nt * 16 + l15;
        int boff = (row * 512 + k * 2) ^ ((row & 7) << 4);
        bX[nt] = *reinterpret_cast<const short8*>((const char*)Xl + boff);
      }
#pragma unroll
      for (int ftl = 0; ftl < 2; ftl++) {
        int f = fc * FFC + wid * 32 + ftl * 16 + l15;
        short8 aW = *reinterpret_cast<const short8*>(W1e + (size_t)f * NC + k);
#pragma unroll
        for (int nt = 0; nt < 4; nt++)
          acc1[ftl][nt] = __builtin_amdgcn_mfma_f32_16x16x32_bf16(aW, bX[nt], acc1[ftl][nt], 0, 0, 0);
      }
    }

    bar_lgkm();   // all waves done reading Hl (previous chunk's GEMM2)

    // ---- bias + gelu -> bf16 Hl[token][f] ----
#pragma unroll
    for (int ftl = 0; ftl < 2; ftl++) {
      int f0 = wid * 32 + ftl * 16 + (lane >> 4) * 4;   // f within chunk
      float4 bv = *reinterpret_cast<const float4*>(b1e + fc * FFC + f0);
#pragma unroll
      for (int nt = 0; nt < 4; nt++) {
        int token = nt * 16 + l15;
        ushort4 hp;
        hp.x = f2b(gelu_f(acc1[ftl][nt][0] + bv.x));
        hp.y = f2b(gelu_f(acc1[ftl][nt][1] + bv.y));
        hp.z = f2b(gelu_f(acc1[ftl][nt][2] + bv.z));
        hp.w = f2b(gelu_f(acc1[ftl][nt][3] + bv.w));
        int boff = (token * 256 + f0 * 2) ^ ((token & 7) << 4);
        *reinterpret_cast<ushort4*>((char*)Hl + boff) = hp;
      }
    }
    bar_lgkm();   // Hl chunk visible to all waves

    // ---- GEMM2: Y[token, c] += H[token, f] * W2[c, f] ----
#pragma unroll
    for (int ks = 0; ks < 4; ks++) {        // K = FFC = 128
      int kf = ks * 32 + kgrp;
      short8 aH[4];
#pragma unroll
      for (int rt = 0; rt < 4; rt++) {
        int row = rt * 16 + l15;
        int boff = (row * 256 + kf * 2) ^ ((row & 7) << 4);
        aH[rt] = *reinterpret_cast<const short8*>((const char*)Hl + boff);
      }
#pragma unroll
      for (int ct = 0; ct < 4; ct++) {
        int c = wid * 64 + ct * 16 + l15;
        short8 bW = *reinterpret_cast<const short8*>(W2e + (size_t)c * NFF + fc * FFC + kf);
#pragma unroll
        for (int rt = 0; rt < 4; rt++)
          acc2[ct][rt] = __builtin_amdgcn_mfma_f32_16x16x32_bf16(aH[rt], bW, acc2[ct][rt], 0, 0, 0);
      }
    }
  }

  // ---- epilogue: out_slot = w * (Y + b2) ----
  float* obase = (slot == 0) ? out0 : out1;
  float bias2[4];
#pragma unroll
  for (int ct = 0; ct < 4; ct++) bias2[ct] = b2e[wid * 64 + ct * 16 + l15];

#pragma unroll
  for (int rt = 0; rt < 4; rt++) {
    if (tile * PPB + rt >= n) continue;
    int pid = pl[rt];
    float wgt = wl[rt];
    int b = pid >> 10, pi = pid & 1023;
    int phi = pi >> 5, pwi = pi & 31;
#pragma unroll
    for (int i = 0; i < 4; i++) {
      int t = (lane >> 4) * 4 + i;   // token within patch
      float* dst =
          obase + (((size_t)(b * NH + phi * 4 + (t >> 2)) * NW) + pwi * 4 + (t & 3)) * NC;
#pragma unroll
      for (int ct = 0; ct < 4; ct++) {
        int c = wid * 64 + ct * 16 + l15;
        float val = wgt * (acc2[ct][rt][i] + bias2[ct]);
        if (mode == 0) dst[c] = val;
        else atomicAdd(&dst[c], val);
      }
    }
  }
}

// ---------------- combine: out += y1 ----------------
__global__ __launch_bounds__(256) void combine_kernel(
    float* __restrict__ out, const float* __restrict__ y1, int n4) {
  int i = blockIdx.x * blockDim.x + threadIdx.x;
  int stride = gridDim.x * blockDim.x;
  for (; i < n4; i += stride) {
    float4 a = reinterpret_cast<float4*>(out)[i];
    float4 b = reinterpret_cast<const float4*>(y1)[i];
    a.x += b.x; a.y += b.y; a.z += b.z; a.w += b.w;
    reinterpret_cast<float4*>(out)[i] = a;
  }
}

extern "C" void kernel_launch(void* const* d_in, const int* in_sizes, int n_in,
                              void* d_out, int out_size, void* d_ws, size_t ws_size,
                              hipStream_t stream) {
  const float* x  = (const float*)d_in[0];
  const float* Wg = (const float*)d_in[1];
  const float* W1 = (const float*)d_in[2];
  const float* b1 = (const float*)d_in[3];
  const float* W2 = (const float*)d_in[4];
  const float* b2 = (const float*)d_in[5];
  float* out = (float*)d_out;

  char* ws = (char*)d_ws;
  unsigned short* W1b = (unsigned short*)ws;                                  // 2 MiB
  unsigned short* W2b = (unsigned short*)(ws + (size_t)2 * 1024 * 1024);      // 2 MiB
  int*   cnt   = (int*)(ws + (size_t)4 * 1024 * 1024);                        // 8 ints
  int*   plist = (int*)(ws + (size_t)4 * 1024 * 1024 + 256);                  // 128 KiB
  float* wlist = (float*)(ws + (size_t)4 * 1024 * 1024 + 256 +
                          (size_t)2 * NE * NPATCH * sizeof(int));             // 128 KiB
  float* y1buf = (float*)(ws + (size_t)8 * 1024 * 1024);                      // 64 MiB

  size_t need = (size_t)8 * 1024 * 1024 + (size_t)NB * NH * NW * NC * sizeof(float);
  int mode = (ws_size >= need) ? 0 : 1;   // 0: slot buffers + combine, 1: atomic

  hipMemsetAsync(cnt, 0, 2 * NE * sizeof(int), stream);
  if (mode == 1)
    hipMemsetAsync(out, 0, (size_t)out_size * sizeof(float), stream);

  convert_kernel<<<dim3(4096), dim3(256), 0, stream>>>(W1, W2, W1b, W2b, NE * NFF * NC);
  router_kernel<<<dim3(NPATCH), dim3(256), 0, stream>>>(x, Wg, cnt, plist, wlist);

  float* out1 = (mode == 0) ? y1buf : out;
  ffn_kernel<<<dim3(8192), dim3(256), 0, stream>>>(
      x, b1, b2, W1b, W2b, cnt, plist, wlist, out, out1, mode);

  if (mode == 0) {
    int n4 = NB * NH * NW * NC / 4;
    combine_kernel<<<dim3(2048), dim3(256), 0, stream>>>(out, y1buf, n4);
  }
}